// Round 18
// baseline (324.424 us; speedup 1.0000x reference)
//
#include <hip/hip_runtime.h>

#define BB 8
#define TIN 168
#define NN 1500
#define TOUTC 24
#define TLEN 162
#define NG 32
#define NTH 768
#define SN 2
#define TOPKK 12
#define NTILE 94   // ceil(1504/16)
#define NPAD 1504

// workspace offsets (in 4-byte elements)
#define OFF_M1   0
#define OFF_M2   24000
#define OFF_M1T  48000
#define OFF_M2T  72000
#define OFF_EW   96000
#define OFF_EB   96112
#define OFF_ADJW 96128
#define OFF_ADJI 115628
#define OFF_FR   135128     // 6 frag planes x 512 ushorts = 1536 floats
#define OFF_S16  136664     // 8*1500*16 = 192000 floats
#define OFF_PART 328664     // 8*32*1500*16 = 6,144,000 floats ([bg][v][16])
// total ws = 6,472,664 floats = 25.9 MB

typedef __attribute__((ext_vector_type(8))) short short8;
typedef __attribute__((ext_vector_type(4))) float v4f;

__device__ __forceinline__ unsigned short f2bf(float f) {
    unsigned int u = __float_as_uint(f);
    unsigned int r = (u + 0x7fffu + ((u >> 16) & 1u)) >> 16;
    return (unsigned short)r;
}
__device__ __forceinline__ unsigned int pack2(float lo, float hi) {
    return (unsigned int)f2bf(lo) | ((unsigned int)f2bf(hi) << 16);
}
__device__ __forceinline__ float unlo(unsigned int u) { return __uint_as_float(u << 16); }
__device__ __forceinline__ float unhi(unsigned int u) { return __uint_as_float(u & 0xffff0000u); }
__device__ __forceinline__ float bf2f(unsigned short s) { return __uint_as_float(((unsigned int)s) << 16); }

__device__ __forceinline__ short8 as_s8(uint4 u) { union { uint4 a; short8 b; } c; c.a = u; return c.b; }

// ---------------- prep: embeddings (+transposed copies) + eff. taps + MFMA weight frags ----------------
__global__ __launch_bounds__(256) void prep_kernel(
    const float* __restrict__ e1, const float* __restrict__ e2,
    const float* __restrict__ gw1, const float* __restrict__ gb1,
    const float* __restrict__ gw2, const float* __restrict__ gb2,
    const float* __restrict__ pw, const float* __restrict__ pb,
    const float* __restrict__ tw2, const float* __restrict__ tb2,
    const float* __restrict__ tw3, const float* __restrict__ tb3,
    const float* __restrict__ tw6, const float* __restrict__ tb6,
    const float* __restrict__ tw7, const float* __restrict__ tb7,
    const float* __restrict__ mw, const float* __restrict__ rw1,
    float* __restrict__ ws)
{
    int n = blockIdx.x * blockDim.x + threadIdx.x;
    if (n < NN) {
        float a1[16], a2[16];
        #pragma unroll
        for (int o = 0; o < 16; ++o) { a1[o] = gb1[o]; a2[o] = gb2[o]; }
        #pragma unroll
        for (int i = 0; i < 16; ++i) {
            float u = e1[n*16+i], v = e2[n*16+i];
            #pragma unroll
            for (int o = 0; o < 16; ++o) {
                a1[o] += u * gw1[i*16+o];
                a2[o] += v * gw2[i*16+o];
            }
        }
        #pragma unroll
        for (int o = 0; o < 16; ++o) {
            float t1v = tanhf(1.5f*a1[o]);
            float t2v = tanhf(1.5f*a2[o]);
            ws[OFF_M1 + n*16+o] = t1v;
            ws[OFF_M2 + n*16+o] = t2v;
            ws[OFF_M1T + o*NN + n] = t1v;   // transposed: coalesced graph reads
            ws[OFF_M2T + o*NN + n] = t2v;
        }
    }
    if (blockIdx.x == 0 && threadIdx.x < 16) {
        int c = threadIdx.x;
        int br = c >> 2, oc = c & 3;
        const float* tw; const float* tb; int k;
        if (br == 0)      { tw = tw2; tb = tb2; k = 2; }
        else if (br == 1) { tw = tw3; tb = tb3; k = 3; }
        else if (br == 2) { tw = tw6; tb = tb6; k = 6; }
        else              { tw = tw7; tb = tb7; k = 7; }
        for (int d = 0; d < 7; ++d) ws[OFF_EW + c*7 + d] = 0.f;
        float ebv = tb[oc];
        for (int j = 0; j < k; ++j) {
            float s = 0.f, sb = 0.f;
            for (int ic = 0; ic < 16; ++ic) {
                float w = tw[(oc*16+ic)*k + j];
                s  += w * pw[ic];
                sb += w * pb[ic];
            }
            ws[OFF_EW + c*7 + (7-k+j)] = s;
            ebv += sb;
        }
        ws[OFF_EB + c] = ebv;
    }
    // MFMA weight fragments (hi/lo bf16 split): A[m=lane&15][k=(lane>>4)*8+j]
    // mat0 = [W1|U] (K=32): W1=M1+0.2(M2+M3), U=0.8M2+0.16M3  (M* = mw 16x16 blocks)
    // mat1 = [V2|0]: V2=0.64M3 ;  mat2 = [rw1|0]
    if (blockIdx.x == 1 && threadIdx.x < 64) {
        int lane = threadIdx.x;
        int m = lane & 15, q = lane >> 4;
        unsigned short* frw = (unsigned short*)(ws + OFF_FR);
        for (int mat = 0; mat < 3; ++mat) {
            for (int j = 0; j < 8; ++j) {
                int k = q*8 + j;
                float s;
                if (mat == 0) s = (k < 16) ? mw[m*48+k] + 0.2f*(mw[m*48+16+k] + mw[m*48+32+k])
                                           : 0.8f*mw[m*48+16+(k-16)] + 0.16f*mw[m*48+32+(k-16)];
                else if (mat == 1) s = (k < 16) ? 0.64f*mw[m*48+32+k] : 0.f;
                else               s = (k < 16) ? rw1[m*16+k] : 0.f;
                unsigned short hi = f2bf(s);
                unsigned short lo = f2bf(s - bf2f(hi));
                frw[(mat*2+0)*512 + lane*8 + j] = hi;
                frw[(mat*2+1)*512 + lane*8 + j] = lo;
            }
        }
    }
}

// ---------------- graph: ONE WAVE PER ROW, no block barriers ----------------
// Scores in 24 regs/lane (j = u*64+lane; ascending u = ascending j -> lowest-index
// tie-break preserved with strict '>'). Per top-k iter: local argmax + 6-step
// shuffle reduce + lane-0 broadcast; owner lane removes + rescans. Winners kept
// in registers; lane 0 writes all 13 adj slots at the end.
__global__ __launch_bounds__(256) void graph_kernel(
    const float* __restrict__ m1, const float* __restrict__ m2,
    const float* __restrict__ m1T, const float* __restrict__ m2T,
    float* __restrict__ adjw, int* __restrict__ adji)
{
    const int lane = threadIdx.x & 63;
    const int wid  = threadIdx.x >> 6;
    const int v = blockIdx.x*4 + wid;
    if (v >= NN) return;

    float m1v[16], m2v[16];
    #pragma unroll
    for (int i = 0; i < 16; ++i) { m1v[i] = m1[v*16+i]; m2v[i] = m2[v*16+i]; }  // wave-uniform -> s_load

    float sreg[24];
    #pragma unroll
    for (int u = 0; u < 24; ++u) {
        int j = u*64 + lane;
        float a = -1.f;
        if (j < NN) {
            float d = 0.f;
            #pragma unroll
            for (int i = 0; i < 16; ++i)
                d += m1v[i]*m2T[i*NN+j] - m2v[i]*m1T[i*NN+j];   // lane-consecutive: full lines
            float t = tanhf(1.5f*d);
            a = t > 0.f ? t : 0.f;
        }
        sreg[u] = a;
    }
    float lb = -1.f; int li = NN;
    #pragma unroll
    for (int u = 0; u < 24; ++u) {
        int j = u*64 + lane;
        if (j < NN && sreg[u] > lb) { lb = sreg[u]; li = j; }
    }

    float bw[TOPKK]; int bidx[TOPKK];
    float wsum = 1.f;
    #pragma unroll
    for (int it = 0; it < TOPKK; ++it) {
        float bv = lb; int bi = li;
        #pragma unroll
        for (int off = 32; off > 0; off >>= 1) {
            float ov = __shfl_down(bv, off);
            int   oi = __shfl_down(bi, off);
            if (ov > bv || (ov == bv && oi < bi)) { bv = ov; bi = oi; }
        }
        bv = __shfl(bv, 0); bi = __shfl(bi, 0);
        bw[it] = bv; bidx[it] = bi; wsum += bv;
        if (li == bi) {   // unique owner (stripes disjoint): remove + rescan
            #pragma unroll
            for (int u = 0; u < 24; ++u)
                if (u*64 + lane == bi) sreg[u] = -1.f;
            lb = -1.f; li = NN;
            #pragma unroll
            for (int u = 0; u < 24; ++u) {
                int j = u*64 + lane;
                if (j < NN && sreg[u] > lb) { lb = sreg[u]; li = j; }
            }
        }
    }
    if (lane == 0) {
        float inv = 1.f/wsum;
        #pragma unroll
        for (int it = 0; it < TOPKK; ++it) {
            adjw[v*13+it] = bw[it]*inv;
            adji[v*13+it] = bidx[it];
        }
        adji[v*13+12] = v;
        adjw[v*13+12] = inv;   // normalized self-loop
    }
}

__device__ __forceinline__ short8 ldfrag(const unsigned short* fr, int plane, int lane) {
    const uint4* p = (const uint4*)(fr + plane*512);
    return as_s8(p[lane]);
}

// ---------------- main (unchanged from R17: 6-plane LDS, 3 barriers/t) ----------------
__global__ __launch_bounds__(NTH, 3) void main_kernel(
    const float* __restrict__ x,
    const float* __restrict__ ew, const float* __restrict__ eb,
    const float* __restrict__ adjw, const int* __restrict__ adji,
    const unsigned short* __restrict__ fr,
    float* __restrict__ part,
    const float* __restrict__ mb, const float* __restrict__ rb1)
{
    __shared__ uint4 feat[6][NPAD];  // 144384 B

    const int tid = threadIdx.x;
    const int lane = tid & 63;
    const int wid = tid >> 6;
    const int b = blockIdx.x >> 5;
    const int g = blockIdx.x & 31;
    const int t0 = (g*TLEN) >> 5;
    const int t1 = ((g+1)*TLEN) >> 5;
    const int n0 = lane & 15, q = lane >> 4;
    float* partBG = part + (size_t)(b*NG + g)*NN*16;

    // ---- prologue: A(t0) -> planes 0,1 ----
    #pragma unroll 1
    for (int s = 0; s < SN; ++s) {
        int v = tid + NTH*s;
        if (v < NN) {
            float xv[7];
            #pragma unroll
            for (int d = 0; d < 7; ++d) xv[d] = x[(b*TIN + t0 + d)*NN + v];
            float h[16];
            #pragma unroll
            for (int c = 0; c < 16; ++c) {
                float a = eb[c];
                #pragma unroll
                for (int d = 0; d < 7; ++d) a += ew[c*7+d]*xv[d];
                h[c] = a > 0.f ? a : 0.f;
            }
            feat[0][v] = make_uint4(pack2(h[0],h[1]), pack2(h[2],h[3]), pack2(h[4],h[5]), pack2(h[6],h[7]));
            feat[1][v] = make_uint4(pack2(h[8],h[9]), pack2(h[10],h[11]), pack2(h[12],h[13]), pack2(h[14],h[15]));
        }
    }
    __syncthreads();

    for (int t = t0; t < t1; ++t) {
        const int par = (t - t0) & 1;
        const int hc = par ? 4 : 0;   // current h1 planes (hc, hc+1)
        const int hn = par ? 0 : 4;   // next    h1 planes

        // ---- B1: u1 = A@h1 (raw weights, incl self-loop) -> planes 2,3 ----
        #pragma unroll 1
        for (int s = 0; s < SN; ++s) {
            int v = tid + NTH*s;
            if (v < NN) {
                float u1[16];
                #pragma unroll
                for (int c = 0; c < 16; ++c) u1[c] = 0.f;
                int base = v*13;
                #pragma unroll
                for (int j = 0; j < 13; ++j) {
                    int nb = adji[base+j];
                    float w = adjw[base+j];
                    uint4 b0 = feat[hc][nb], b1 = feat[hc+1][nb];
                    unsigned int uu[8] = {b0.x,b0.y,b0.z,b0.w,b1.x,b1.y,b1.z,b1.w};
                    #pragma unroll
                    for (int i = 0; i < 8; ++i) { u1[2*i] += w*unlo(uu[i]); u1[2*i+1] += w*unhi(uu[i]); }
                }
                feat[2][v] = make_uint4(pack2(u1[0],u1[1]), pack2(u1[2],u1[3]), pack2(u1[4],u1[5]), pack2(u1[6],u1[7]));
                feat[3][v] = make_uint4(pack2(u1[8],u1[9]), pack2(u1[10],u1[11]), pack2(u1[12],u1[13]), pack2(u1[14],u1[15]));
            }
        }
        __syncthreads();

        // ---- B2 (MFMA): z -> bf16 half-slots over h1 planes; p -> u1 planes ----
        {
            short8 a1h = ldfrag(fr, 0, lane), a1l = ldfrag(fr, 1, lane);
            short8 a2h = ldfrag(fr, 2, lane), a2l = ldfrag(fr, 3, lane);
            ushort4* zH = (ushort4*)feat[hc + (q >> 1)];
            ushort4* pH = (ushort4*)feat[2  + (q >> 1)];
            #pragma unroll 1
            for (int T = wid; T < NTILE; T += 12) {
                int n = T*16 + n0;
                short8 bf  = as_s8(feat[(q < 2) ? (hc + q) : q][n]);  // K-quads: h1,h1,u1,u1
                short8 b2f = as_s8(feat[2 + (q & 1)][n]);             // u1 (upper-K weights 0)
                v4f z = {0.f,0.f,0.f,0.f}, p = {0.f,0.f,0.f,0.f};
                z = __builtin_amdgcn_mfma_f32_16x16x32_bf16(a1h, bf, z, 0, 0, 0);
                z = __builtin_amdgcn_mfma_f32_16x16x32_bf16(a1l, bf, z, 0, 0, 0);
                p = __builtin_amdgcn_mfma_f32_16x16x32_bf16(a2h, b2f, p, 0, 0, 0);
                p = __builtin_amdgcn_mfma_f32_16x16x32_bf16(a2l, b2f, p, 0, 0, 0);
                ushort4 zz; zz.x = f2bf(z[0]); zz.y = f2bf(z[1]); zz.z = f2bf(z[2]); zz.w = f2bf(z[3]);
                ushort4 pp; pp.x = f2bf(p[0]); pp.y = f2bf(p[1]); pp.z = f2bf(p[2]); pp.w = f2bf(p[3]);
                zH[n*2 + (q & 1)] = zz;
                pH[n*2 + (q & 1)] = pp;
            }
        }
        __syncthreads();

        // ---- D: A(t+1) -> hn planes ; lane-layout D1 ; wave-local D2 MFMA ; part RMW ----
        if (t + 1 < t1) {
            #pragma unroll 1
            for (int s = 0; s < SN; ++s) {
                int v = tid + NTH*s;
                if (v < NN) {
                    float xv[7];
                    #pragma unroll
                    for (int d = 0; d < 7; ++d) xv[d] = x[(b*TIN + (t+1) + d)*NN + v];
                    float h[16];
                    #pragma unroll
                    for (int c = 0; c < 16; ++c) {
                        float a = eb[c];
                        #pragma unroll
                        for (int d = 0; d < 7; ++d) a += ew[c*7+d]*xv[d];
                        h[c] = a > 0.f ? a : 0.f;
                    }
                    feat[hn][v]   = make_uint4(pack2(h[0],h[1]), pack2(h[2],h[3]), pack2(h[4],h[5]), pack2(h[6],h[7]));
                    feat[hn+1][v] = make_uint4(pack2(h[8],h[9]), pack2(h[10],h[11]), pack2(h[12],h[13]), pack2(h[14],h[15]));
                }
            }
        }
        {
            short8 a3h = ldfrag(fr, 4, lane), a3l = ldfrag(fr, 5, lane);
            float mbq[4], rbq[4];
            #pragma unroll
            for (int r = 0; r < 4; ++r) { mbq[r] = mb[q*4+r]; rbq[r] = rb1[q*4+r]; }
            ushort4* zH = (ushort4*)feat[hc + (q >> 1)];
            const ushort4* pH = (const ushort4*)feat[2 + (q >> 1)];
            #pragma unroll 1
            for (int T = wid; T < NTILE; T += 12) {
                int n = T*16 + n0;
                ushort4 zz = zH[n*2 + (q & 1)];
                float y0 = mbq[0] + bf2f(zz.x);
                float y1 = mbq[1] + bf2f(zz.y);
                float y2 = mbq[2] + bf2f(zz.z);
                float y3 = mbq[3] + bf2f(zz.w);
                int base = (n < NN ? n : NN-1) * 13;   // clamp: keep adj/LDS reads in range
                #pragma unroll
                for (int j = 0; j < 13; ++j) {
                    int nb = adji[base+j];
                    float w = adjw[base+j];
                    ushort4 ps = pH[nb*2 + (q & 1)];
                    y0 += w*bf2f(ps.x); y1 += w*bf2f(ps.y);
                    y2 += w*bf2f(ps.z); y3 += w*bf2f(ps.w);
                }
                y0 = y0 > 0.f ? y0 : 0.f;  y1 = y1 > 0.f ? y1 : 0.f;
                y2 = y2 > 0.f ? y2 : 0.f;  y3 = y3 > 0.f ? y3 : 0.f;
                ushort4 yy; yy.x = f2bf(y0); yy.y = f2bf(y1); yy.z = f2bf(y2); yy.w = f2bf(y3);
                zH[n*2 + (q & 1)] = yy;
                short8 bfY = as_s8(feat[(q < 2) ? (hc + q) : q][n]);
                v4f acc = {0.f,0.f,0.f,0.f};
                acc = __builtin_amdgcn_mfma_f32_16x16x32_bf16(a3h, bfY, acc, 0, 0, 0);
                acc = __builtin_amdgcn_mfma_f32_16x16x32_bf16(a3l, bfY, acc, 0, 0, 0);
                if (n < NN) {
                    float r0 = acc[0]+rbq[0], r1 = acc[1]+rbq[1], r2 = acc[2]+rbq[2], r3 = acc[3]+rbq[3];
                    r0 = r0 > 0.f ? r0 : 0.f;  r1 = r1 > 0.f ? r1 : 0.f;
                    r2 = r2 > 0.f ? r2 : 0.f;  r3 = r3 > 0.f ? r3 : 0.f;
                    float4* pp = (float4*)(partBG + (size_t)n*16 + q*4);
                    if (t == t0) {
                        *pp = make_float4(r0, r1, r2, r3);
                    } else {
                        float4 o = *pp;
                        *pp = make_float4(o.x+r0, o.y+r1, o.z+r2, o.w+r3);
                    }
                }
            }
        }
        __syncthreads();
    }
}

// ---------------- reduce1: sum over 32 g (coalesced), scale 1/162 ----------------
__global__ __launch_bounds__(256) void reduce1_kernel(const float* __restrict__ part,
                                                      float* __restrict__ s16buf)
{
    int idx = blockIdx.x*256 + threadIdx.x;     // over (b*NN+v)*16+c
    if (idx >= BB*NN*16) return;
    int c = idx & 15;
    int rest = idx >> 4;
    int v = rest % NN;
    int b = rest / NN;
    float s = 0.f;
    #pragma unroll
    for (int g = 0; g < NG; ++g)
        s += part[((size_t)(b*NG + g)*NN + v)*16 + c];
    s16buf[idx] = s * (1.0f/TLEN);
}

// ---------------- reduce2: out = rw2 @ s16 + rb2 ----------------
__global__ __launch_bounds__(256) void reduce2_kernel(const float* __restrict__ s16buf,
                                                      const float* __restrict__ rw2,
                                                      const float* __restrict__ rb2,
                                                      float* __restrict__ out)
{
    int idx = blockIdx.x*256 + threadIdx.x;     // over b*NN+v
    if (idx >= BB*NN) return;
    int v = idx % NN;
    int b = idx / NN;
    const float4* sp = (const float4*)(s16buf + (size_t)idx*16);
    float4 s0 = sp[0], s1 = sp[1], s2 = sp[2], s3 = sp[3];
    float s16[16] = {s0.x,s0.y,s0.z,s0.w, s1.x,s1.y,s1.z,s1.w,
                     s2.x,s2.y,s2.z,s2.w, s3.x,s3.y,s3.z,s3.w};
    #pragma unroll
    for (int o = 0; o < TOUTC; ++o) {
        float a = rb2[o];
        #pragma unroll
        for (int c = 0; c < 16; ++c) a += rw2[o*16+c]*s16[c];
        out[(b*TOUTC + o)*NN + v] = a;
    }
}

extern "C" void kernel_launch(void* const* d_in, const int* in_sizes, int n_in,
                              void* d_out, int out_size, void* d_ws, size_t ws_size,
                              hipStream_t stream)
{
    const float* x   = (const float*)d_in[0];
    const float* pw  = (const float*)d_in[1];
    const float* pb  = (const float*)d_in[2];
    const float* tw2 = (const float*)d_in[3];
    const float* tb2 = (const float*)d_in[4];
    const float* tw3 = (const float*)d_in[5];
    const float* tb3 = (const float*)d_in[6];
    const float* tw6 = (const float*)d_in[7];
    const float* tb6 = (const float*)d_in[8];
    const float* tw7 = (const float*)d_in[9];
    const float* tb7 = (const float*)d_in[10];
    const float* e1  = (const float*)d_in[11];
    const float* e2  = (const float*)d_in[12];
    const float* gw1 = (const float*)d_in[13];
    const float* gb1 = (const float*)d_in[14];
    const float* gw2 = (const float*)d_in[15];
    const float* gb2 = (const float*)d_in[16];
    const float* mw  = (const float*)d_in[17];
    const float* mb  = (const float*)d_in[18];
    const float* rw1 = (const float*)d_in[19];
    const float* rb1 = (const float*)d_in[20];
    const float* rw2 = (const float*)d_in[21];
    const float* rb2 = (const float*)d_in[22];
    float* ws  = (float*)d_ws;
    float* out = (float*)d_out;

    prep_kernel<<<(NN + 255)/256, 256, 0, stream>>>(e1,e2,gw1,gb1,gw2,gb2,pw,pb,
                                                    tw2,tb2,tw3,tb3,tw6,tb6,tw7,tb7,
                                                    mw, rw1, ws);
    graph_kernel<<<(NN + 3)/4, 256, 0, stream>>>(ws + OFF_M1, ws + OFF_M2,
                                                 ws + OFF_M1T, ws + OFF_M2T,
                                                 ws + OFF_ADJW, (int*)ws + OFF_ADJI);
    main_kernel<<<BB*NG, NTH, 0, stream>>>(x, ws + OFF_EW, ws + OFF_EB,
                                           ws + OFF_ADJW, (const int*)ws + OFF_ADJI,
                                           (const unsigned short*)(ws + OFF_FR),
                                           ws + OFF_PART, mb, rb1);
    reduce1_kernel<<<(BB*NN*16 + 255)/256, 256, 0, stream>>>(ws + OFF_PART, ws + OFF_S16);
    reduce2_kernel<<<(BB*NN + 255)/256, 256, 0, stream>>>(ws + OFF_S16, rw2, rb2, out);
}